// Round 8
// baseline (1972.336 us; speedup 1.0000x reference)
//
#include <hip/hip_runtime.h>

typedef unsigned int u32;
typedef unsigned long long u64;

#define CH_ 128
#define TAIL_M 16384u
#define MAX_ROUNDS 4000
#define BT 4
#define NBLK 128

__device__ __forceinline__ u32 f2ord(float f){
  u32 u = __float_as_uint(f);
  return ((int)u < 0) ? ~u : (u | 0x80000000u);
}
__device__ __forceinline__ float ord2f(u32 u){
  return (u & 0x80000000u) ? __uint_as_float(u & 0x7FFFFFFFu) : __uint_as_float(~u);
}
__device__ __forceinline__ u32 ldu32(const u32* p){
  return __hip_atomic_load(p, __ATOMIC_RELAXED, __HIP_MEMORY_SCOPE_AGENT);
}
__device__ __forceinline__ void stu32(u32* p, u32 v){
  __hip_atomic_store(p, v, __ATOMIC_RELAXED, __HIP_MEMORY_SCOPE_AGENT);
}
__device__ __forceinline__ void stu64(u64* p, u64 v){
  __hip_atomic_store(p, v, __ATOMIC_RELAXED, __HIP_MEMORY_SCOPE_AGENT);
}
// agent-scope (LLC write-through) 16B entry store as two u64 relaxed atomics.
__device__ __forceinline__ void ste(uint4* p, uint4 v){
  u64* q = (u64*)p;
  stu64(q,     (u64)v.x | ((u64)v.y << 32));
  stu64(q + 1, (u64)v.z | ((u64)v.w << 32));
}
// atomicMax with cheap hi-word pre-check. Plain (possibly stale) load is
// monotonicity-safe: stale <= current, so skipping when stale_hi > k_hi is safe.
__device__ __forceinline__ void amax64(u64* a, u64 k){
  u32 hi = ((const u32*)a)[1];
  if (hi <= (u32)(k >> 32)) atomicMax((unsigned long long*)a, (unsigned long long)k);
}
// Grid barrier with acquire-invalidate (proven correct in round 7).
__device__ __forceinline__ void gbar(u32* arrive, u32 target){
  asm volatile("s_waitcnt vmcnt(0) lgkmcnt(0)" ::: "memory");
  __syncthreads();
  if (threadIdx.x == 0){
    __hip_atomic_fetch_add(arrive, 1u, __ATOMIC_RELAXED, __HIP_MEMORY_SCOPE_AGENT);
    while (ldu32(arrive) < target) __builtin_amdgcn_s_sleep(2);
    __builtin_amdgcn_fence(__ATOMIC_ACQUIRE, "agent");
  }
  __syncthreads();
}

// ---------------- init ----------------
__global__ void k_init(u32* hdr, u32* mxbits, double* den, u64* b0, u64* b1,
                       int* craw, int* medge, int N){
  int i0 = blockIdx.x*blockDim.x + threadIdx.x;
  int nt = gridDim.x*blockDim.x;
  for (int v = i0; v < N; v += nt){
    mxbits[v]=0u; den[v]=0.0; b0[v]=0ull; b1[v]=0ull; craw[v]=v; medge[v]=-1;
  }
  if (i0 == 0){
    for (int i = 0; i < 64; i++) hdr[i] = 0u;
    hdr[6] = (u32)N;
  }
}

__global__ void k_init2(u32* hist, u32* cur2, u32* uniqcnt, int n){
  int i = blockIdx.x*blockDim.x + threadIdx.x;
  if (i < n){ hist[i]=0u; cur2[i]=0u; uniqcnt[i]=0u; }
}

// ---------------- per-node dot products: s=x.w1, t=x.w2 ----------------
__global__ void k_dots(const float* __restrict__ x, const float* __restrict__ lw,
                       float* __restrict__ s, float* __restrict__ t, int N){
  int wid = threadIdx.x >> 6, lane = threadIdx.x & 63;
  int node = blockIdx.x*4 + wid;
  if (node >= N) return;
  const float* xr = x + (size_t)node*CH_;
  float xa = xr[lane], xb = xr[64+lane];
  float sv = xa*lw[lane]      + xb*lw[64+lane];
  float tv = xa*lw[128+lane]  + xb*lw[192+lane];
  #pragma unroll
  for (int m = 1; m < 64; m <<= 1){ sv += __shfl_xor(sv, m); tv += __shfl_xor(tv, m); }
  if (lane == 0){ s[node]=sv; t[node]=tv; }
}

// ---------------- raw score + segment max over col ----------------
__global__ void k_rawmax(const float* __restrict__ s, const float* __restrict__ t,
                         const int* __restrict__ row, const int* __restrict__ col,
                         const float* __restrict__ lb, float* __restrict__ rawex,
                         u32* __restrict__ mxbits, int E){
  float b = lb[0];
  int i0 = blockIdx.x*blockDim.x + threadIdx.x;
  int nt = gridDim.x*blockDim.x;
  for (int e = i0; e < E; e += nt){
    float raw = (s[row[e]] + t[col[e]]) + b;
    rawex[e] = raw;
    atomicMax(&mxbits[col[e]], f2ord(raw));
  }
}

// ---------------- ex = exp(raw-mx), den = segsum(ex) in f64 ----------------
__global__ void k_exden(const int* __restrict__ col, const u32* __restrict__ mxbits,
                        float* __restrict__ rawex, double* __restrict__ den, int E){
  int i0 = blockIdx.x*blockDim.x + threadIdx.x;
  int nt = gridDim.x*blockDim.x;
  for (int e = i0; e < E; e += nt){
    int c = col[e];
    float ex = expf(rawex[e] - ord2f(mxbits[c]));
    rawex[e] = ex;
    atomicAdd(&den[c], (double)ex);
  }
}

// ---------------- score (in-place), packed entries, seed b0 (round 0) ----
__global__ void k_scorekey(const int* __restrict__ row, const int* __restrict__ col,
                           float* __restrict__ rawex, const double* __restrict__ den,
                           u32* __restrict__ rc, uint4* __restrict__ Alin,
                           u64* b0, int E){
  int i0 = blockIdx.x*blockDim.x + threadIdx.x;
  int nt = gridDim.x*blockDim.x;
  for (int e = i0; e < E; e += nt){
    int r = row[e], c = col[e];
    float d = (float)den[c];
    float sc = rawex[e]/d + 0.5f;          // > 0 -> float bits order-monotone
    rawex[e] = sc;
    u32 sb = __float_as_uint(sc);
    rc[e] = ((u32)r << 16) | (u32)c;        // N < 65536
    Alin[e] = make_uint4((u32)e, (u32)r, (u32)c, sb);
    u64 k = (1ull << 52) | ((u64)sb << 20) | (u64)(0xFFFFFu - (u32)e);
    amax64(b0 + r, k);
    amax64(b0 + c, k);
  }
}

// ---------------- cooperative matching ----------------
__global__ void __launch_bounds__(1024)
k_match(u32* hdr, const u32* __restrict__ rc, u64* b0, u64* b1,
        int* __restrict__ craw, int* __restrict__ medge,
        const uint4* __restrict__ Alin, uint4* Aseg0, uint4* Aseg1,
        u32* bcntA, u32* bcntB, int E, u32 cap){
  __shared__ u64 skey[16384];        // 128 KB (tail sort)
  __shared__ u32 usedbm[2048];       // 8 KB bitmap (N <= 65536)
  __shared__ u32 pre[NBLK + 1];
  __shared__ u32 lcount;

  u32* arrive = hdr + 32;
  u32 tid = (u32)(blockIdx.x*blockDim.x + threadIdx.x);
  u32 nt  = (u32)(gridDim.x*blockDim.x);
  int lane = threadIdx.x & 63;
  u32 bc_round = 0;
  u32 m = (u32)E;
  int R = 0;

  // ---- grid phase ----
  while (R < MAX_ROUNDS){
    bool lin = (R == 0);
    const uint4* cur = lin ? Alin : ((R & 1) ? Aseg1 : Aseg0);
    uint4* dstb = ((R & 1) ? Aseg0 : Aseg1) + (size_t)blockIdx.x * cap;
    u32* bc_cur = (R & 1) ? bcntB : bcntA;
    u32* bc_dst = (R & 1) ? bcntA : bcntB;
    u64* cb = (R & 1) ? b1 : b0;
    u64* nb = (R & 1) ? b0 : b1;

    if (!lin){
      // prefix of per-block survivor counts (wave 0)
      if (threadIdx.x < 64){
        u32 a = bc_cur[lane];
        u32 b = bc_cur[64 + lane];
        #pragma unroll
        for (int o = 1; o < 64; o <<= 1){ u32 t = (u32)__shfl_up((int)a, o); if (lane >= o) a += t; }
        u32 tot0 = (u32)__shfl((int)a, 63);
        #pragma unroll
        for (int o = 1; o < 64; o <<= 1){ u32 t = (u32)__shfl_up((int)b, o); if (lane >= o) b += t; }
        pre[1 + lane] = a;
        pre[65 + lane] = tot0 + b;
        if (lane == 0) pre[0] = 0;
      }
      __syncthreads();
      m = pre[NBLK];
    }
    if (m <= TAIL_M) break;

    if (threadIdx.x == 0) lcount = 0;
    __syncthreads();

    u64 kpfx = ((u64)(R + 1)) << 52;
    u32 chunk = nt * (u32)BT;
    for (u32 base = 0; base < m; base += chunk){
      uint4 en[BT]; bool val[BT]; bool two[BT];
      u64 w1[BT], w2[BT]; u32 p1[BT], p2[BT];
      u64 br[BT], bc[BT];
      u64 q1r[BT], q1c[BT], q2r[BT], q2c[BT];
      // stage 1: entry loads (virtual index -> segmented slot)
      #pragma unroll
      for (int j = 0; j < BT; j++){
        u32 i = base + tid + (u32)j*nt;
        val[j] = (i < m);
        if (val[j]){
          u32 idx = i;
          if (!lin){
            u32 lo = 0, hi = NBLK;
            while (hi - lo > 1){ u32 mid = (lo + hi) >> 1; if (pre[mid] <= i) lo = mid; else hi = mid; }
            idx = lo * cap + (i - pre[lo]);
          }
          en[j] = cur[idx];
        }
      }
      // stage 2: best-buffer loads
      #pragma unroll
      for (int j = 0; j < BT; j++) if (val[j]){
        br[j] = cb[en[j].y];
        bc[j] = cb[en[j].z];
      }
      // stage 3: classify; matched edges resolve now
      #pragma unroll
      for (int j = 0; j < BT; j++) if (val[j]){
        u64 k = kpfx | ((u64)en[j].w << 20) | (u64)(0xFFFFFu - en[j].x);
        if (br[j] == k && bc[j] == k){
          craw[en[j].z] = (int)en[j].y; medge[en[j].y] = (int)en[j].x;
          val[j] = false;
        } else if (br[j] == k){ w1[j] = bc[j]; two[j] = false; }
        else if (bc[j] == k || bc[j] == br[j]){ w1[j] = br[j]; two[j] = false; }
        else { w1[j] = br[j]; w2[j] = bc[j]; two[j] = true; }
      }
      // stage 4: winner endpoint lookups
      #pragma unroll
      for (int j = 0; j < BT; j++) if (val[j]){
        p1[j] = rc[0xFFFFFu - (u32)(w1[j] & 0xFFFFFu)];
        if (two[j]) p2[j] = rc[0xFFFFFu - (u32)(w2[j] & 0xFFFFFu)];
      }
      // stage 5: winner mutual-dominance loads
      #pragma unroll
      for (int j = 0; j < BT; j++) if (val[j]){
        q1r[j] = cb[p1[j] >> 16];
        q1c[j] = cb[p1[j] & 0xFFFFu];
        if (two[j]){ q2r[j] = cb[p2[j] >> 16]; q2c[j] = cb[p2[j] & 0xFFFFu]; }
      }
      // stage 6: resolve survivors (per-block region, LDS counter)
      #pragma unroll
      for (int j = 0; j < BT; j++) if (val[j]){
        bool dead = (q1r[j] == w1[j]) & (q1c[j] == w1[j]);
        if (two[j]) dead = dead || ((q2r[j] == w2[j]) & (q2c[j] == w2[j]));
        if (!dead){
          u32 off = atomicAdd(&lcount, 1u);
          ste(dstb + off, en[j]);
          u64 k2 = (kpfx + (1ull << 52)) | ((u64)en[j].w << 20) | (u64)(0xFFFFFu - en[j].x);
          amax64(nb + en[j].y, k2);
          amax64(nb + en[j].z, k2);
        }
      }
    }
    __syncthreads();
    if (threadIdx.x == 0) stu32(&bc_dst[blockIdx.x], lcount);
    bc_round++; gbar(arrive, bc_round * (u32)NBLK);
    R++;
  }

  // ---- one-shot exact tail: sort survivors desc, sequential greedy ----
  if (blockIdx.x != 0) return;
  {
    bool lin = (R == 0);
    const uint4* cur = lin ? Alin : ((R & 1) ? Aseg1 : Aseg0);
    u32 msz = 64; while (msz < m) msz <<= 1;
    for (u32 i = threadIdx.x; i < msz; i += 1024){
      u64 kk = 0ull;
      if (i < m){
        u32 idx = i;
        if (!lin){
          u32 lo = 0, hi = NBLK;
          while (hi - lo > 1){ u32 mid = (lo + hi) >> 1; if (pre[mid] <= i) lo = mid; else hi = mid; }
          idx = lo * cap + (i - pre[lo]);
        }
        uint4 en = cur[idx];
        kk = ((u64)en.w << 20) | (u64)(0xFFFFFu - en.x);
      }
      skey[i] = kk;
    }
    for (u32 i = threadIdx.x; i < 2048; i += 1024) usedbm[i] = 0u;
    __syncthreads();
    if (m){
      // bitonic sort, descending (zero pads sink to the end)
      for (u32 kk2 = 2; kk2 <= msz; kk2 <<= 1){
        for (u32 jj = kk2 >> 1; jj > 0; jj >>= 1){
          for (u32 i = threadIdx.x; i < msz; i += 1024){
            u32 ix = i ^ jj;
            if (ix > i){
              u64 a = skey[i], b = skey[ix];
              bool desc = ((i & kk2) == 0);
              if (desc ? (a < b) : (a > b)){ skey[i] = b; skey[ix] = a; }
            }
          }
          __syncthreads();
        }
      }
      // wave 0: exact sequential greedy over sorted list
      if (threadIdx.x < 64){
        for (u32 base = 0; base < m; base += 64){
          u32 ii = base + (u32)lane;
          u64 kk = (ii < msz) ? skey[ii] : 0ull;
          bool have = (kk != 0ull) && (ii < m);
          u32 e = 0u, r = 0xFFFFFFFFu, c = 0xFFFFFFFFu;
          if (have){ e = 0xFFFFFu - (u32)(kk & 0xFFFFFu); u32 p = rc[e]; r = p >> 16; c = p & 0xFFFFu; }
          u64 hmask = __ballot(have);
          u64 cmask = 0ull;
          for (int l = 0; l < 64; l++){
            u32 rl = (u32)__shfl((int)r, l), cl = (u32)__shfl((int)c, l);
            bool cf = (l != lane) && ((r == rl) | (r == cl) | (c == rl) | (c == cl));
            cmask |= ((u64)cf) << l;
          }
          cmask &= hmask;
          bool free0 = false;
          if (have) free0 = !((usedbm[r >> 5] >> (r & 31)) & 1u) &&
                            !((usedbm[c >> 5] >> (c & 31)) & 1u);
          u64 lower = (1ull << lane) - 1ull;
          u64 det = ~hmask, acc = 0ull;
          while (det != ~0ull){
            bool undet = !((det >> lane) & 1ull);
            bool ready = undet && ((cmask & lower & ~det) == 0ull);
            bool myacc = ready && free0 && ((cmask & lower & acc) == 0ull);
            det |= __ballot(ready);
            acc |= __ballot(myacc);
          }
          if ((acc >> lane) & 1ull){
            atomicOr(&usedbm[r >> 5], 1u << (r & 31));
            atomicOr(&usedbm[c >> 5], 1u << (c & 31));
            craw[c] = (int)r; medge[r] = (int)e;
          }
          asm volatile("s_waitcnt lgkmcnt(0)" ::: "memory");
        }
      }
    }
  }
}

__global__ void k_rootflag(const int* __restrict__ craw, u32* __restrict__ rf, int N){
  int i = blockIdx.x*blockDim.x + threadIdx.x;
  if (i < N) rf[i] = (craw[i] == i) ? 1u : 0u;
}

// ---------------- generic exclusive scan (n <= 65536) ----------------
__global__ void scan_p1(const u32* __restrict__ in, u32* __restrict__ out,
                        u32* __restrict__ bsums, const u32* __restrict__ nptr){
  __shared__ u32 sh[256];
  u32 n = *nptr;
  int t = threadIdx.x;
  u32 i = blockIdx.x*256u + (u32)t;
  u32 v = (i < n) ? in[i] : 0u;
  sh[t] = v; __syncthreads();
  for (int o = 1; o < 256; o <<= 1){
    u32 a = (t >= o) ? sh[t-o] : 0u;
    __syncthreads();
    sh[t] += a;
    __syncthreads();
  }
  if (i < n) out[i] = sh[t] - v;
  if (t == 255) bsums[blockIdx.x] = sh[255];
}
__global__ void scan_p2(u32* bsums, u32* total){
  __shared__ u32 sh[256];
  int t = threadIdx.x;
  u32 v = bsums[t];
  sh[t] = v; __syncthreads();
  for (int o = 1; o < 256; o <<= 1){
    u32 a = (t >= o) ? sh[t-o] : 0u;
    __syncthreads();
    sh[t] += a;
    __syncthreads();
  }
  bsums[t] = sh[t] - v;
  if (t == 255 && total) *total = sh[255];
}
__global__ void scan_p3(u32* out, const u32* __restrict__ bsums, const u32* __restrict__ nptr){
  u32 n = *nptr;
  u32 i = blockIdx.x*256u + threadIdx.x;
  if (i < n) out[i] += bsums[blockIdx.x];
}

// ---------------- final cluster ids (+ write cluster output) ----------------
__global__ void k_clusterout(const int* __restrict__ craw, const u32* __restrict__ newid,
                             int* __restrict__ clout, float* __restrict__ out,
                             size_t offC, int N){
  int i = blockIdx.x*blockDim.x + threadIdx.x;
  if (i < N){
    int cl = (int)newid[craw[i]];
    clout[i] = cl;
    out[offC + i] = (float)cl;
  }
}

__global__ void k_hist(const int* __restrict__ row, const int* __restrict__ clout,
                       u32* __restrict__ hist, int E){
  int i0 = blockIdx.x*blockDim.x + threadIdx.x;
  int nt = gridDim.x*blockDim.x;
  for (int e = i0; e < E; e += nt) atomicAdd(&hist[clout[row[e]]], 1u);
}

__global__ void k_scatter(const int* __restrict__ row, const int* __restrict__ col,
                          const int* __restrict__ clout, const u32* __restrict__ segoff,
                          u32* __restrict__ cur2, u32* __restrict__ ccbuf, int E){
  int i0 = blockIdx.x*blockDim.x + threadIdx.x;
  int nt = gridDim.x*blockDim.x;
  for (int e = i0; e < E; e += nt){
    int cr = clout[row[e]];
    u32 pos = segoff[cr] + atomicAdd(&cur2[cr], 1u);
    ccbuf[pos] = (u32)clout[col[e]];
  }
}

// ---------------- per-segment sort + dedup (1 wave / block) ----------------
__global__ void k_segsort(const u32* __restrict__ hdr, const u32* __restrict__ hist,
                          const u32* __restrict__ segoff, u32* __restrict__ ccbuf,
                          u32* __restrict__ uniqcnt){
  int c = (int)hdr[2];
  __shared__ u32 sh[1024];
  int lane = threadIdx.x;   // block = 64 threads
  for (int seg = blockIdx.x; seg < c; seg += gridDim.x){
    int n = (int)hist[seg];
    if (n <= 0){ if (lane == 0) uniqcnt[seg] = 0u; continue; }
    u32 off = segoff[seg];
    if (n <= 64){
      u32 v = (lane < n) ? ccbuf[off + lane] : 0xFFFFFFFFu;
      #pragma unroll
      for (int k = 2; k <= 64; k <<= 1)
        for (int j = k >> 1; j > 0; j >>= 1){
          u32 p = __shfl_xor(v, j);
          bool up  = ((lane & k) == 0);
          bool low = ((lane & j) == 0);
          u32 mn = v < p ? v : p, mx = v < p ? p : v;
          v = (up == low) ? mn : mx;
        }
      u32 pv = __shfl_up(v, 1);
      bool un = (lane < n) && (lane == 0 || v != pv);
      u64 bal = __ballot(un);
      int cnt = __popcll(bal);
      int rk  = __popcll(bal & ((1ull << lane) - 1ull));
      if (un) ccbuf[off + rk] = v;
      if (lane == 0) uniqcnt[seg] = (u32)cnt;
    } else {
      int nn = n > 1024 ? 1024 : n;
      for (int i = lane; i < nn; i += 64) sh[i] = ccbuf[off + i];
      __syncthreads();
      for (int p = 0; p < nn; p++){
        int st = p & 1;
        for (int i = lane; 2*i + 1 + st < nn; i += 64){
          int a = 2*i + st;
          u32 x0 = sh[a], x1 = sh[a+1];
          if (x0 > x1){ sh[a] = x1; sh[a+1] = x0; }
        }
        __syncthreads();
      }
      if (lane == 0){
        int cnt = 0; u32 prev = 0u;
        for (int i = 0; i < nn; i++){
          u32 xv = sh[i];
          if (i == 0 || xv != prev){ ccbuf[off + cnt] = xv; cnt++; prev = xv; }
        }
        uniqcnt[seg] = (u32)cnt;
      }
      __syncthreads();
    }
  }
}

// ---------------- write new_edge_index ----------------
__global__ void k_writeedges(const u32* __restrict__ hdr, const u32* __restrict__ segoff,
                             const u32* __restrict__ uniqcnt, const u32* __restrict__ uniqoff,
                             const u32* __restrict__ ccbuf, float* __restrict__ out){
  int c = (int)hdr[2]; u32 Ep = hdr[3];
  size_t base = (size_t)c * CH_;
  int gw   = (blockIdx.x*blockDim.x + threadIdx.x) >> 6;
  int lane = threadIdx.x & 63;
  int nw   = (gridDim.x*blockDim.x) >> 6;
  for (int seg = gw; seg < c; seg += nw){
    int cnt = (int)uniqcnt[seg];
    u32 so = segoff[seg], uo = uniqoff[seg];
    for (int j = lane; j < cnt; j += 64){
      u32 cc = ccbuf[so + j];
      out[base + uo + j]              = (float)seg;
      out[base + (size_t)Ep + uo + j] = (float)cc;
    }
  }
}

// ---------------- new_x / new_batch / new_edge_score (wave per root) ----------------
__global__ void k_final(const u32* __restrict__ hdr, const int* __restrict__ craw,
                        const u32* __restrict__ newid, const int* __restrict__ medge,
                        const int* __restrict__ row, const int* __restrict__ col,
                        const float* __restrict__ score, const int* __restrict__ batch,
                        const float* __restrict__ x, float* __restrict__ out, int N){
  int c = (int)hdr[2]; u32 Ep = hdr[3];
  size_t offB = (size_t)c * CH_ + 2ull * (size_t)Ep;
  size_t offS = offB + (size_t)c;
  int gw   = (blockIdx.x*blockDim.x + threadIdx.x) >> 6;
  int lane = threadIdx.x & 63;
  int nw   = (gridDim.x*blockDim.x) >> 6;
  for (int i = gw; i < N; i += nw){
    if (craw[i] != i) continue;
    int j = (int)newid[i];
    int e = medge[i];
    int lo = i, hi = i; float sc = 1.0f;
    if (e >= 0){
      int r = row[e], cc = col[e];
      lo = min(r, cc); hi = max(r, cc);
      sc = score[e];
    }
    float v0 = x[(size_t)lo*CH_ + lane];
    float v1 = x[(size_t)lo*CH_ + 64 + lane];
    if (hi != lo){ v0 += x[(size_t)hi*CH_ + lane]; v1 += x[(size_t)hi*CH_ + 64 + lane]; }
    out[(size_t)j*CH_ + lane]      = v0 * sc;
    out[(size_t)j*CH_ + 64 + lane] = v1 * sc;
    if (lane == 0){
      out[offB + j] = (float)batch[hi];  // CPU-XLA scatter: last (max-index) member wins
      out[offS + j] = sc;
    }
  }
}

extern "C" void kernel_launch(void* const* d_in, const int* in_sizes, int n_in,
                              void* d_out, int out_size, void* d_ws, size_t ws_size,
                              hipStream_t stream) {
  const float* x     = (const float*)d_in[0];
  const int*   eidx  = (const int*)d_in[1];
  const int*   batch = (const int*)d_in[2];
  const float* lw    = (const float*)d_in[3];
  const float* lb    = (const float*)d_in[4];

  int N = in_sizes[0] / CH_;
  int E = in_sizes[1] / 2;
  const int* row = eidx;
  const int* col = eidx + E;
  float* out = (float*)d_out;

  u32 nt = (u32)NBLK * 1024u;
  u32 chunks = ((u32)E + nt*BT - 1u) / (nt*BT);
  u32 cap = chunks * 1024u * BT;      // max entries one block can produce per round

  // ---- workspace carve ----
  char* w = (char*)d_ws;
  size_t off = 0;
  auto carve = [&](size_t bytes) -> void* {
    void* p = w + off;
    off += (bytes + 255) & ~(size_t)255;
    return p;
  };
  u32*    hdr    = (u32*)   carve(256);
  double* den    = (double*)carve((size_t)N*8);
  u64*    b0     = (u64*)   carve((size_t)N*8);
  u64*    b1     = (u64*)   carve((size_t)N*8);
  float*  s      = (float*) carve((size_t)N*4);
  float*  t      = (float*) carve((size_t)N*4);
  float*  rawex  = (float*) carve((size_t)E*4);   // becomes score
  u32*    mxbits = (u32*)   carve((size_t)N*4);
  int*    craw   = (int*)   carve((size_t)N*4);
  u32*    rf     = (u32*)   carve((size_t)N*4);
  u32*    newid  = (u32*)   carve((size_t)N*4);
  int*    medge  = (int*)   carve((size_t)N*4);
  int*    clout  = (int*)   carve((size_t)N*4);
  u32*    rc     = (u32*)   carve((size_t)E*4);
  u32*    bcntA  = (u32*)   carve((size_t)NBLK*4);
  u32*    bcntB  = (u32*)   carve((size_t)NBLK*4);
  uint4*  Alin   = (uint4*) carve((size_t)E*16);
  uint4*  Aseg0  = (uint4*) carve((size_t)cap*NBLK*16);
  uint4*  Aseg1  = (uint4*) carve((size_t)cap*NBLK*16);
  u32*    bsums  = (u32*)   carve(256*4);
  // alias post-match scratch into the (then-dead) Alin region
  char* a = (char*)Alin;
  size_t aoff = 0;
  auto acarve = [&](size_t bytes) -> void* {
    void* p = a + aoff;
    aoff += (bytes + 255) & ~(size_t)255;
    return p;
  };
  u32* ccbuf   = (u32*)acarve((size_t)E*4);
  u32* hist    = (u32*)acarve((size_t)(N+64)*4);
  u32* segoff  = (u32*)acarve((size_t)(N+64)*4);
  u32* cur2    = (u32*)acarve((size_t)(N+64)*4);
  u32* uniqcnt = (u32*)acarve((size_t)(N+64)*4);
  u32* uniqoff = (u32*)acarve((size_t)(N+64)*4);
  (void)ws_size; (void)n_in;

  int nbE = (E + 255) / 256;
  int nbN = (N + 255) / 256;

  k_init<<<512, 256, 0, stream>>>(hdr, mxbits, den, b0, b1, craw, medge, N);
  k_dots<<<(N + 3)/4, 256, 0, stream>>>(x, lw, s, t, N);
  k_rawmax<<<nbE, 256, 0, stream>>>(s, t, row, col, lb, rawex, mxbits, E);
  k_exden<<<nbE, 256, 0, stream>>>(col, mxbits, rawex, den, E);
  k_scorekey<<<nbE, 256, 0, stream>>>(row, col, rawex, den, rc, Alin, b0, E);

  {
    void* kargs[] = { &hdr, (void*)&rc, &b0, &b1, &craw, &medge,
                      (void*)&Alin, &Aseg0, &Aseg1, &bcntA, &bcntB, &E, &cap };
    hipLaunchCooperativeKernel((void*)k_match, dim3(NBLK), dim3(1024), kargs, 0, stream);
  }

  k_rootflag<<<nbN, 256, 0, stream>>>(craw, rf, N);

  // scan rootflag -> newid ; total -> hdr[2] (= c). n from hdr[6] (= N)
  scan_p1<<<256, 256, 0, stream>>>(rf, newid, bsums, &hdr[6]);
  scan_p2<<<1, 256, 0, stream>>>(bsums, &hdr[2]);
  scan_p3<<<256, 256, 0, stream>>>(newid, bsums, &hdr[6]);

  k_clusterout<<<nbN, 256, 0, stream>>>(craw, newid, clout, out, (size_t)(out_size - N), N);
  k_init2<<<(N + 64 + 255)/256, 256, 0, stream>>>(hist, cur2, uniqcnt, N + 64);
  k_hist<<<nbE, 256, 0, stream>>>(row, clout, hist, E);

  // scan hist -> segoff ; n from hdr[2] (= c)
  scan_p1<<<256, 256, 0, stream>>>(hist, segoff, bsums, &hdr[2]);
  scan_p2<<<1, 256, 0, stream>>>(bsums, &hdr[4]);
  scan_p3<<<256, 256, 0, stream>>>(segoff, bsums, &hdr[2]);

  k_scatter<<<nbE, 256, 0, stream>>>(row, col, clout, segoff, cur2, ccbuf, E);
  k_segsort<<<4096, 64, 0, stream>>>(hdr, hist, segoff, ccbuf, uniqcnt);

  // scan uniqcnt -> uniqoff ; total -> hdr[3] (= E')
  scan_p1<<<256, 256, 0, stream>>>(uniqcnt, uniqoff, bsums, &hdr[2]);
  scan_p2<<<1, 256, 0, stream>>>(bsums, &hdr[3]);
  scan_p3<<<256, 256, 0, stream>>>(uniqoff, bsums, &hdr[2]);

  k_writeedges<<<2048, 256, 0, stream>>>(hdr, segoff, uniqcnt, uniqoff, ccbuf, out);
  k_final<<<4096, 256, 0, stream>>>(hdr, craw, newid, medge, row, col, rawex, batch, x, out, N);
}

// Round 9
// 563.305 us; speedup vs baseline: 3.5014x; 3.5014x over previous
//
#include <hip/hip_runtime.h>

typedef unsigned int u32;
typedef unsigned long long u64;

#define CH_ 128

__device__ __forceinline__ u32 f2ord(float f){
  u32 u = __float_as_uint(f);
  return ((int)u < 0) ? ~u : (u | 0x80000000u);
}
__device__ __forceinline__ float ord2f(u32 u){
  return (u & 0x80000000u) ? __uint_as_float(u & 0x7FFFFFFFu) : __uint_as_float(~u);
}

// ---------------- init ----------------
__global__ void k_init(u32* hdr, u32* mxbits, double* den, u64* sw,
                       int* craw, int* medge, u32* deg, u32* acur,
                       u32* offarr, int N, int E){
  int i0 = blockIdx.x*blockDim.x + threadIdx.x;
  int nt = gridDim.x*blockDim.x;
  for (int v = i0; v < N; v += nt){
    mxbits[v]=0u; den[v]=0.0; sw[v]=0ull; craw[v]=v; medge[v]=-1;
    deg[v]=0u; acur[v]=0u;
  }
  if (i0 == 0){
    for (int i = 0; i < 64; i++) hdr[i] = 0u;
    hdr[6] = (u32)N;
    offarr[N] = (u32)(2*E);     // off[N] sentinel; scan writes only [0,N)
  }
}

__global__ void k_init2(u32* hist, u32* cur2, u32* uniqcnt, int n){
  int i = blockIdx.x*blockDim.x + threadIdx.x;
  if (i < n){ hist[i]=0u; cur2[i]=0u; uniqcnt[i]=0u; }
}

// ---------------- per-node dot products: s=x.w1, t=x.w2 ----------------
__global__ void k_dots(const float* __restrict__ x, const float* __restrict__ lw,
                       float* __restrict__ s, float* __restrict__ t, int N){
  int wid = threadIdx.x >> 6, lane = threadIdx.x & 63;
  int node = blockIdx.x*4 + wid;
  if (node >= N) return;
  const float* xr = x + (size_t)node*CH_;
  float xa = xr[lane], xb = xr[64+lane];
  float sv = xa*lw[lane]      + xb*lw[64+lane];
  float tv = xa*lw[128+lane]  + xb*lw[192+lane];
  #pragma unroll
  for (int m = 1; m < 64; m <<= 1){ sv += __shfl_xor(sv, m); tv += __shfl_xor(tv, m); }
  if (lane == 0){ s[node]=sv; t[node]=tv; }
}

// ---------------- raw score + segment max over col ----------------
__global__ void k_rawmax(const float* __restrict__ s, const float* __restrict__ t,
                         const int* __restrict__ row, const int* __restrict__ col,
                         const float* __restrict__ lb, float* __restrict__ rawex,
                         u32* __restrict__ mxbits, int E){
  float b = lb[0];
  int i0 = blockIdx.x*blockDim.x + threadIdx.x;
  int nt = gridDim.x*blockDim.x;
  for (int e = i0; e < E; e += nt){
    float raw = (s[row[e]] + t[col[e]]) + b;
    rawex[e] = raw;
    atomicMax(&mxbits[col[e]], f2ord(raw));
  }
}

// ---------------- ex = exp(raw-mx), den = segsum(ex) in f64 ----------------
__global__ void k_exden(const int* __restrict__ col, const u32* __restrict__ mxbits,
                        float* __restrict__ rawex, double* __restrict__ den, int E){
  int i0 = blockIdx.x*blockDim.x + threadIdx.x;
  int nt = gridDim.x*blockDim.x;
  for (int e = i0; e < E; e += nt){
    int c = col[e];
    float ex = expf(rawex[e] - ord2f(mxbits[c]));
    rawex[e] = ex;
    atomicAdd(&den[c], (double)ex);
  }
}

// ---------------- score (in-place), rc pack, degree histogram ----------------
__global__ void k_scorekey(const int* __restrict__ row, const int* __restrict__ col,
                           float* __restrict__ rawex, const double* __restrict__ den,
                           u32* __restrict__ rc, u32* __restrict__ deg, int E){
  int i0 = blockIdx.x*blockDim.x + threadIdx.x;
  int nt = gridDim.x*blockDim.x;
  for (int e = i0; e < E; e += nt){
    int r = row[e], c = col[e];
    float d = (float)den[c];
    float sc = rawex[e]/d + 0.5f;          // > 0 -> float bits order-monotone
    rawex[e] = sc;                          // rawex now holds the score
    rc[e] = ((u32)r << 16) | (u32)c;        // N < 65536
    atomicAdd(&deg[r], 1u);
    atomicAdd(&deg[c], 1u);
  }
}

// ---------------- CSR scatter: adjacency of keys ----------------
__global__ void k_adjscatter(const u32* __restrict__ rc, const float* __restrict__ score,
                             const u32* __restrict__ offarr, u32* __restrict__ acur,
                             u64* __restrict__ adj, int E){
  int i0 = blockIdx.x*blockDim.x + threadIdx.x;
  int nt = gridDim.x*blockDim.x;
  for (int e = i0; e < E; e += nt){
    u32 p = rc[e]; u32 r = p >> 16, c = p & 0xFFFFu;
    u64 k = ((u64)__float_as_uint(score[e]) << 20) | (u64)(0xFFFFFu - (u32)e);
    adj[offarr[r] + atomicAdd(&acur[r], 1u)] = k;
    adj[offarr[c] + atomicAdd(&acur[c], 1u)] = k;
  }
}

// ---------------- per-vertex adjacency sort (descending key) ----------------
__global__ void k_adjsort(const u32* __restrict__ offarr, u64* __restrict__ adj, int N){
  __shared__ u64 sh[512];
  int lane = threadIdx.x;    // block = 64 threads (1 wave)
  for (int seg = blockIdx.x; seg < N; seg += gridDim.x){
    u32 base = offarr[seg];
    int n = (int)(offarr[seg+1] - base);
    if (n <= 1) continue;
    if (n <= 64){
      u64 v = (lane < n) ? adj[base + lane] : 0ull;
      #pragma unroll
      for (int k2 = 2; k2 <= 64; k2 <<= 1)
        for (int j = k2 >> 1; j > 0; j >>= 1){
          u64 p = __shfl_xor(v, j);
          bool up  = ((lane & k2) == 0);
          bool low = ((lane & j) == 0);
          u64 mx = v > p ? v : p, mn = v > p ? p : v;
          v = (up == low) ? mx : mn;     // descending
        }
      if (lane < n) adj[base + lane] = v;
    } else {
      int msz = 128; while (msz < n) msz <<= 1;   // n <= 512 (Poisson(32) max ~60)
      for (int i = lane; i < msz; i += 64) sh[i] = (i < n) ? adj[base + i] : 0ull;
      __syncthreads();
      for (int k2 = 2; k2 <= msz; k2 <<= 1){
        for (int j = k2 >> 1; j > 0; j >>= 1){
          for (int i = lane; i < msz; i += 64){
            int ix = i ^ j;
            if (ix > i){
              u64 a = sh[i], b = sh[ix];
              bool desc = ((i & k2) == 0);
              if (desc ? (a < b) : (a > b)){ sh[i] = b; sh[ix] = a; }
            }
          }
          __syncthreads();
        }
      }
      for (int i = lane; i < n; i += 64) adj[base + i] = sh[i];
      __syncthreads();
    }
  }
}

// ---------------- async suitor matching (== sequential greedy for unique keys) ----
// Each vertex scans its desc-sorted list; propose = atomicMax(&sw[v], key).
// Displaced proposer is adopted by the displacing thread; pointers never rewind.
// Plain loads of sw are monotone-safe (stale <= current): skip only when
// stale >= k implies current >= k; otherwise the atomicMax is authoritative.
__global__ void k_suitor(const u32* __restrict__ rc, const u32* __restrict__ offarr,
                         const u64* __restrict__ adj, u64* sw, int N){
  int i0 = blockIdx.x*blockDim.x + threadIdx.x;
  int nt = gridDim.x*blockDim.x;
  for (int v0 = i0; v0 < N; v0 += nt){
    u32 u = (u32)v0;
    u32 pos = offarr[u], end = offarr[u+1];
    while (pos < end){
      u64 k = adj[pos]; pos++;
      u32 e = 0xFFFFFu - (u32)(k & 0xFFFFFu);
      u32 p = rc[e];
      u32 v = ((p >> 16) == u) ? (p & 0xFFFFu) : (p >> 16);
      if (sw[v] >= k) continue;                       // monotone-safe pre-check
      u64 old = atomicMax((unsigned long long*)&sw[v], (unsigned long long)k);
      if (old >= k) continue;                         // lost the race
      if (old == 0ull) break;                         // accepted, nobody displaced
      // adopt displaced proposer w of edge(old)
      u32 e2 = 0xFFFFFu - (u32)(old & 0xFFFFFu);
      u32 p2 = rc[e2];
      u = ((p2 >> 16) == v) ? (p2 & 0xFFFFu) : (p2 >> 16);
      u32 lo = offarr[u]; end = offarr[u+1]; u32 hi = end;
      while (lo < hi){ u32 mid = (lo + hi) >> 1; if (adj[mid] > old) lo = mid + 1; else hi = mid; }
      pos = lo + 1;                                   // resume after the displaced edge
    }
  }
}

// ---------------- extract matching: mutual suitor pairs ----------------
__global__ void k_extract(const u64* __restrict__ sw, const u32* __restrict__ rc,
                          int* __restrict__ craw, int* __restrict__ medge, int N){
  int v = blockIdx.x*blockDim.x + threadIdx.x;
  if (v >= N) return;
  u64 k = sw[v];
  if (k == 0ull) return;
  u32 e = 0xFFFFFu - (u32)(k & 0xFFFFFu);
  u32 p = rc[e]; u32 r = p >> 16, c = p & 0xFFFFu;
  if ((u32)v == c && sw[r] == k && sw[c] == k){
    craw[c] = (int)r; medge[r] = (int)e;
  }
}

__global__ void k_rootflag(const int* __restrict__ craw, u32* __restrict__ rf, int N){
  int i = blockIdx.x*blockDim.x + threadIdx.x;
  if (i < N) rf[i] = (craw[i] == i) ? 1u : 0u;
}

// ---------------- generic exclusive scan (n <= 65536) ----------------
__global__ void scan_p1(const u32* __restrict__ in, u32* __restrict__ out,
                        u32* __restrict__ bsums, const u32* __restrict__ nptr){
  __shared__ u32 sh[256];
  u32 n = *nptr;
  int t = threadIdx.x;
  u32 i = blockIdx.x*256u + (u32)t;
  u32 v = (i < n) ? in[i] : 0u;
  sh[t] = v; __syncthreads();
  for (int o = 1; o < 256; o <<= 1){
    u32 a = (t >= o) ? sh[t-o] : 0u;
    __syncthreads();
    sh[t] += a;
    __syncthreads();
  }
  if (i < n) out[i] = sh[t] - v;
  if (t == 255) bsums[blockIdx.x] = sh[255];
}
__global__ void scan_p2(u32* bsums, u32* total){
  __shared__ u32 sh[256];
  int t = threadIdx.x;
  u32 v = bsums[t];
  sh[t] = v; __syncthreads();
  for (int o = 1; o < 256; o <<= 1){
    u32 a = (t >= o) ? sh[t-o] : 0u;
    __syncthreads();
    sh[t] += a;
    __syncthreads();
  }
  bsums[t] = sh[t] - v;
  if (t == 255 && total) *total = sh[255];
}
__global__ void scan_p3(u32* out, const u32* __restrict__ bsums, const u32* __restrict__ nptr){
  u32 n = *nptr;
  u32 i = blockIdx.x*256u + threadIdx.x;
  if (i < n) out[i] += bsums[blockIdx.x];
}

// ---------------- final cluster ids (+ write cluster output) ----------------
__global__ void k_clusterout(const int* __restrict__ craw, const u32* __restrict__ newid,
                             int* __restrict__ clout, float* __restrict__ out,
                             size_t offC, int N){
  int i = blockIdx.x*blockDim.x + threadIdx.x;
  if (i < N){
    int cl = (int)newid[craw[i]];
    clout[i] = cl;
    out[offC + i] = (float)cl;
  }
}

__global__ void k_hist(const int* __restrict__ row, const int* __restrict__ clout,
                       u32* __restrict__ hist, int E){
  int i0 = blockIdx.x*blockDim.x + threadIdx.x;
  int nt = gridDim.x*blockDim.x;
  for (int e = i0; e < E; e += nt) atomicAdd(&hist[clout[row[e]]], 1u);
}

__global__ void k_scatter(const int* __restrict__ row, const int* __restrict__ col,
                          const int* __restrict__ clout, const u32* __restrict__ segoff,
                          u32* __restrict__ cur2, u32* __restrict__ ccbuf, int E){
  int i0 = blockIdx.x*blockDim.x + threadIdx.x;
  int nt = gridDim.x*blockDim.x;
  for (int e = i0; e < E; e += nt){
    int cr = clout[row[e]];
    u32 pos = segoff[cr] + atomicAdd(&cur2[cr], 1u);
    ccbuf[pos] = (u32)clout[col[e]];
  }
}

// ---------------- per-segment sort + dedup (1 wave / block) ----------------
__global__ void k_segsort(const u32* __restrict__ hdr, const u32* __restrict__ hist,
                          const u32* __restrict__ segoff, u32* __restrict__ ccbuf,
                          u32* __restrict__ uniqcnt){
  int c = (int)hdr[2];
  __shared__ u32 sh[1024];
  int lane = threadIdx.x;   // block = 64 threads
  for (int seg = blockIdx.x; seg < c; seg += gridDim.x){
    int n = (int)hist[seg];
    if (n <= 0){ if (lane == 0) uniqcnt[seg] = 0u; continue; }
    u32 off = segoff[seg];
    if (n <= 64){
      u32 v = (lane < n) ? ccbuf[off + lane] : 0xFFFFFFFFu;
      #pragma unroll
      for (int k = 2; k <= 64; k <<= 1)
        for (int j = k >> 1; j > 0; j >>= 1){
          u32 p = __shfl_xor(v, j);
          bool up  = ((lane & k) == 0);
          bool low = ((lane & j) == 0);
          u32 mn = v < p ? v : p, mx = v < p ? p : v;
          v = (up == low) ? mn : mx;
        }
      u32 pv = __shfl_up(v, 1);
      bool un = (lane < n) && (lane == 0 || v != pv);
      u64 bal = __ballot(un);
      int cnt = __popcll(bal);
      int rk  = __popcll(bal & ((1ull << lane) - 1ull));
      if (un) ccbuf[off + rk] = v;
      if (lane == 0) uniqcnt[seg] = (u32)cnt;
    } else {
      int nn = n > 1024 ? 1024 : n;
      for (int i = lane; i < nn; i += 64) sh[i] = ccbuf[off + i];
      __syncthreads();
      for (int p = 0; p < nn; p++){
        int st = p & 1;
        for (int i = lane; 2*i + 1 + st < nn; i += 64){
          int a = 2*i + st;
          u32 x0 = sh[a], x1 = sh[a+1];
          if (x0 > x1){ sh[a] = x1; sh[a+1] = x0; }
        }
        __syncthreads();
      }
      if (lane == 0){
        int cnt = 0; u32 prev = 0u;
        for (int i = 0; i < nn; i++){
          u32 xv = sh[i];
          if (i == 0 || xv != prev){ ccbuf[off + cnt] = xv; cnt++; prev = xv; }
        }
        uniqcnt[seg] = (u32)cnt;
      }
      __syncthreads();
    }
  }
}

// ---------------- write new_edge_index ----------------
__global__ void k_writeedges(const u32* __restrict__ hdr, const u32* __restrict__ segoff,
                             const u32* __restrict__ uniqcnt, const u32* __restrict__ uniqoff,
                             const u32* __restrict__ ccbuf, float* __restrict__ out){
  int c = (int)hdr[2]; u32 Ep = hdr[3];
  size_t base = (size_t)c * CH_;
  int gw   = (blockIdx.x*blockDim.x + threadIdx.x) >> 6;
  int lane = threadIdx.x & 63;
  int nw   = (gridDim.x*blockDim.x) >> 6;
  for (int seg = gw; seg < c; seg += nw){
    int cnt = (int)uniqcnt[seg];
    u32 so = segoff[seg], uo = uniqoff[seg];
    for (int j = lane; j < cnt; j += 64){
      u32 cc = ccbuf[so + j];
      out[base + uo + j]              = (float)seg;
      out[base + (size_t)Ep + uo + j] = (float)cc;
    }
  }
}

// ---------------- new_x / new_batch / new_edge_score (wave per root) ----------------
__global__ void k_final(const u32* __restrict__ hdr, const int* __restrict__ craw,
                        const u32* __restrict__ newid, const int* __restrict__ medge,
                        const int* __restrict__ row, const int* __restrict__ col,
                        const float* __restrict__ score, const int* __restrict__ batch,
                        const float* __restrict__ x, float* __restrict__ out, int N){
  int c = (int)hdr[2]; u32 Ep = hdr[3];
  size_t offB = (size_t)c * CH_ + 2ull * (size_t)Ep;
  size_t offS = offB + (size_t)c;
  int gw   = (blockIdx.x*blockDim.x + threadIdx.x) >> 6;
  int lane = threadIdx.x & 63;
  int nw   = (gridDim.x*blockDim.x) >> 6;
  for (int i = gw; i < N; i += nw){
    if (craw[i] != i) continue;
    int j = (int)newid[i];
    int e = medge[i];
    int lo = i, hi = i; float sc = 1.0f;
    if (e >= 0){
      int r = row[e], cc = col[e];
      lo = min(r, cc); hi = max(r, cc);
      sc = score[e];
    }
    float v0 = x[(size_t)lo*CH_ + lane];
    float v1 = x[(size_t)lo*CH_ + 64 + lane];
    if (hi != lo){ v0 += x[(size_t)hi*CH_ + lane]; v1 += x[(size_t)hi*CH_ + 64 + lane]; }
    out[(size_t)j*CH_ + lane]      = v0 * sc;
    out[(size_t)j*CH_ + 64 + lane] = v1 * sc;
    if (lane == 0){
      out[offB + j] = (float)batch[hi];  // CPU-XLA scatter: last (max-index) member wins
      out[offS + j] = sc;
    }
  }
}

extern "C" void kernel_launch(void* const* d_in, const int* in_sizes, int n_in,
                              void* d_out, int out_size, void* d_ws, size_t ws_size,
                              hipStream_t stream) {
  const float* x     = (const float*)d_in[0];
  const int*   eidx  = (const int*)d_in[1];
  const int*   batch = (const int*)d_in[2];
  const float* lw    = (const float*)d_in[3];
  const float* lb    = (const float*)d_in[4];

  int N = in_sizes[0] / CH_;
  int E = in_sizes[1] / 2;
  const int* row = eidx;
  const int* col = eidx + E;
  float* out = (float*)d_out;

  // ---- workspace carve ----
  char* w = (char*)d_ws;
  size_t off = 0;
  auto carve = [&](size_t bytes) -> void* {
    void* p = w + off;
    off += (bytes + 255) & ~(size_t)255;
    return p;
  };
  u32*    hdr    = (u32*)   carve(256);
  double* den    = (double*)carve((size_t)N*8);
  u64*    sw     = (u64*)   carve((size_t)N*8);
  float*  s      = (float*) carve((size_t)N*4);
  float*  t      = (float*) carve((size_t)N*4);
  float*  rawex  = (float*) carve((size_t)E*4);   // becomes score
  u32*    mxbits = (u32*)   carve((size_t)N*4);
  int*    craw   = (int*)   carve((size_t)N*4);
  u32*    rf     = (u32*)   carve((size_t)N*4);
  u32*    newid  = (u32*)   carve((size_t)N*4);
  int*    medge  = (int*)   carve((size_t)N*4);
  int*    clout  = (int*)   carve((size_t)N*4);
  u32*    rc     = (u32*)   carve((size_t)E*4);
  u32*    deg    = (u32*)   carve((size_t)N*4);
  u32*    acur   = (u32*)   carve((size_t)N*4);
  u32*    offarr = (u32*)   carve((size_t)(N+1)*4);
  u64*    adj    = (u64*)   carve((size_t)(2*(size_t)E)*8);
  u32*    bsums  = (u32*)   carve(256*4);
  // alias post-match scratch into the (then-dead) adj region
  char* a = (char*)adj;
  size_t aoff = 0;
  auto acarve = [&](size_t bytes) -> void* {
    void* p = a + aoff;
    aoff += (bytes + 255) & ~(size_t)255;
    return p;
  };
  u32* ccbuf   = (u32*)acarve((size_t)E*4);
  u32* hist    = (u32*)acarve((size_t)(N+64)*4);
  u32* segoff  = (u32*)acarve((size_t)(N+64)*4);
  u32* cur2    = (u32*)acarve((size_t)(N+64)*4);
  u32* uniqcnt = (u32*)acarve((size_t)(N+64)*4);
  u32* uniqoff = (u32*)acarve((size_t)(N+64)*4);
  (void)ws_size; (void)n_in;

  int nbE = (E + 255) / 256;
  int nbN = (N + 255) / 256;

  k_init<<<512, 256, 0, stream>>>(hdr, mxbits, den, sw, craw, medge, deg, acur, offarr, N, E);
  k_dots<<<(N + 3)/4, 256, 0, stream>>>(x, lw, s, t, N);
  k_rawmax<<<nbE, 256, 0, stream>>>(s, t, row, col, lb, rawex, mxbits, E);
  k_exden<<<nbE, 256, 0, stream>>>(col, mxbits, rawex, den, E);
  k_scorekey<<<nbE, 256, 0, stream>>>(row, col, rawex, den, rc, deg, E);

  // scan deg -> offarr (exclusive); n from hdr[6] (= N); total -> hdr[7] (unused)
  scan_p1<<<256, 256, 0, stream>>>(deg, offarr, bsums, &hdr[6]);
  scan_p2<<<1, 256, 0, stream>>>(bsums, &hdr[7]);
  scan_p3<<<256, 256, 0, stream>>>(offarr, bsums, &hdr[6]);

  k_adjscatter<<<nbE, 256, 0, stream>>>(rc, rawex, offarr, acur, adj, E);
  k_adjsort<<<4096, 64, 0, stream>>>(offarr, adj, N);
  k_suitor<<<nbN, 256, 0, stream>>>(rc, offarr, adj, sw, N);
  k_extract<<<nbN, 256, 0, stream>>>(sw, rc, craw, medge, N);

  k_rootflag<<<nbN, 256, 0, stream>>>(craw, rf, N);

  // scan rootflag -> newid ; total -> hdr[2] (= c)
  scan_p1<<<256, 256, 0, stream>>>(rf, newid, bsums, &hdr[6]);
  scan_p2<<<1, 256, 0, stream>>>(bsums, &hdr[2]);
  scan_p3<<<256, 256, 0, stream>>>(newid, bsums, &hdr[6]);

  k_clusterout<<<nbN, 256, 0, stream>>>(craw, newid, clout, out, (size_t)(out_size - N), N);
  k_init2<<<(N + 64 + 255)/256, 256, 0, stream>>>(hist, cur2, uniqcnt, N + 64);
  k_hist<<<nbE, 256, 0, stream>>>(row, clout, hist, E);

  // scan hist -> segoff ; n from hdr[2] (= c)
  scan_p1<<<256, 256, 0, stream>>>(hist, segoff, bsums, &hdr[2]);
  scan_p2<<<1, 256, 0, stream>>>(bsums, &hdr[4]);
  scan_p3<<<256, 256, 0, stream>>>(segoff, bsums, &hdr[2]);

  k_scatter<<<nbE, 256, 0, stream>>>(row, col, clout, segoff, cur2, ccbuf, E);
  k_segsort<<<4096, 64, 0, stream>>>(hdr, hist, segoff, ccbuf, uniqcnt);

  // scan uniqcnt -> uniqoff ; total -> hdr[3] (= E')
  scan_p1<<<256, 256, 0, stream>>>(uniqcnt, uniqoff, bsums, &hdr[2]);
  scan_p2<<<1, 256, 0, stream>>>(bsums, &hdr[3]);
  scan_p3<<<256, 256, 0, stream>>>(uniqoff, bsums, &hdr[2]);

  k_writeedges<<<2048, 256, 0, stream>>>(hdr, segoff, uniqcnt, uniqoff, ccbuf, out);
  k_final<<<4096, 256, 0, stream>>>(hdr, craw, newid, medge, row, col, rawex, batch, x, out, N);
}